// Round 1
// baseline (221.555 us; speedup 1.0000x reference)
//
#include <hip/hip_runtime.h>
#include <hip/hip_bf16.h>
#include <math.h>

// Problem constants (BlockSoftmaxLinearHybrid: B=2,H=16,L=4096,D=64,F=64,S=64)
constexpr int Bc = 2, Hc = 16, Lc = 4096, Dc = 64, Fc = 64;
constexpr int Sc = 64;
constexpr int Nc = Lc / Sc;          // 64 blocks along L
constexpr int F2 = 2 * Fc;           // 128
constexpr int BH = Bc * Hc;          // 32
constexpr int NBLK = BH * Nc;        // 2048 tiles
constexpr float EPSf = 1e-6f;
constexpr float SCALE = 0.125f;      // D^-0.5
constexpr int RP = 68;               // padded row stride (floats); 68*4B=272B = 17*16B (16B-aligned rows)

// ---------------------------------------------------------------------------
// passA: per tile (bh,n) compute phi(k) and write dS = phi_k^T @ v (128x64),
//        dZ = sum_s phi_k (128) to workspace.
// ---------------------------------------------------------------------------
__global__ __launch_bounds__(256) void passA(const float* __restrict__ K,
                                             const float* __restrict__ V,
                                             const float* __restrict__ W,
                                             float* __restrict__ wsS,
                                             float* __restrict__ wsZ)
{
    // stage1: sK [64][68] @0, sW [64][64] @4352   (8448 floats)
    // stage2: sPhiT [128][68] @0, sV [64][68] @8704  (13056 floats)
    __shared__ float lds[13056];
    float* sK   = lds;
    float* sW   = lds + 4352;
    float* sPhiT= lds;
    float* sV   = lds + 8704;

    const int t   = threadIdx.x;
    const int bid = blockIdx.x;          // bh*64 + n
    const int bh  = bid >> 6;
    const int h   = bh & (Hc - 1);
    const long base = (long)bh * Lc * Dc + (long)(bid & 63) * Sc * Dc;

    {
        const float4* Kg = (const float4*)(K + base);
        const float4* Wg = (const float4*)(W + (long)h * Dc * Fc);
        #pragma unroll
        for (int i = 0; i < 4; ++i) {
            int e = t + i * 256;              // float4 index over 4096 floats
            float4 kv = Kg[e];
            int s = e >> 4;                    // (4e)/64
            int d = (e & 15) * 4;
            *(float4*)&sK[s * RP + d] = kv;
            *(float4*)&sW[e * 4] = Wg[e];
        }
    }
    __syncthreads();

    // u[s][f] = sum_d k[s][d] * W[d][f]; thread (s = t>>2, cols f0..f0+15)
    const int s  = t >> 2;
    const int f0 = (t & 3) * 16;
    float u[16];
    #pragma unroll
    for (int j = 0; j < 16; ++j) u[j] = 0.f;
    for (int d = 0; d < Dc; ++d) {
        float kv = sK[s * RP + d];
        const float* wrow = &sW[d * Fc + f0];
        #pragma unroll
        for (int j4 = 0; j4 < 4; ++j4) {
            float4 w4 = *(const float4*)&wrow[j4 * 4];
            u[j4*4+0] += kv * w4.x;
            u[j4*4+1] += kv * w4.y;
            u[j4*4+2] += kv * w4.z;
            u[j4*4+3] += kv * w4.w;
        }
    }
    // row softmax(+u) and softmax(-u) over f (64), row spread across 4 lanes
    float mx = u[0], mn = u[0];
    #pragma unroll
    for (int j = 1; j < 16; ++j) { mx = fmaxf(mx, u[j]); mn = fminf(mn, u[j]); }
    mx = fmaxf(mx, __shfl_xor(mx, 1, 4)); mx = fmaxf(mx, __shfl_xor(mx, 2, 4));
    mn = fminf(mn, __shfl_xor(mn, 1, 4)); mn = fminf(mn, __shfl_xor(mn, 2, 4));
    float pp[16], pn[16];
    float sp = 0.f, sn = 0.f;
    #pragma unroll
    for (int j = 0; j < 16; ++j) {
        pp[j] = expf(u[j] - mx); sp += pp[j];
        pn[j] = expf(mn - u[j]); sn += pn[j];
    }
    sp += __shfl_xor(sp, 1, 4); sp += __shfl_xor(sp, 2, 4);
    sn += __shfl_xor(sn, 1, 4); sn += __shfl_xor(sn, 2, 4);
    const float rpi = 1.f / sp, rni = 1.f / sn;

    __syncthreads();   // done reading sK/sW; safe to overwrite

    // write phi transposed: phiT[f][s], f in [0,128)
    #pragma unroll
    for (int j = 0; j < 16; ++j) {
        sPhiT[(f0 + j) * RP + s]      = pp[j] * rpi;
        sPhiT[(Fc + f0 + j) * RP + s] = pn[j] * rni;
    }
    // load v [64][68]
    {
        const float4* Vg = (const float4*)(V + base);
        #pragma unroll
        for (int i = 0; i < 4; ++i) {
            int e = t + i * 256;
            float4 vv = Vg[e];
            int ss = e >> 4;
            int dd = (e & 15) * 4;
            *(float4*)&sV[ss * RP + dd] = vv;
        }
    }
    __syncthreads();

    // dS[f][d] = sum_s phiT[f][s] * v[s][d]; thread: d = t&63, f block = (t>>6)*32
    const int d_    = t & 63;
    const int fbase = (t >> 6) * 32;
    float acc[32];
    #pragma unroll
    for (int i = 0; i < 32; ++i) acc[i] = 0.f;
    for (int sc4 = 0; sc4 < 16; ++sc4) {
        float v0 = sV[(sc4*4+0) * RP + d_];
        float v1 = sV[(sc4*4+1) * RP + d_];
        float v2 = sV[(sc4*4+2) * RP + d_];
        float v3 = sV[(sc4*4+3) * RP + d_];
        #pragma unroll
        for (int fi = 0; fi < 32; ++fi) {
            float4 p4 = *(const float4*)&sPhiT[(fbase + fi) * RP + sc4 * 4];
            acc[fi] += p4.x * v0 + p4.y * v1 + p4.z * v2 + p4.w * v3;
        }
    }
    float* outS = wsS + (long)bid * (F2 * Dc);
    #pragma unroll
    for (int fi = 0; fi < 32; ++fi)
        outS[(fbase + fi) * Dc + d_] = acc[fi];

    if (t < F2) {
        float z = 0.f;
        #pragma unroll
        for (int i = 0; i < 16; ++i) {
            float4 p4 = *(const float4*)&sPhiT[t * RP + i * 4];
            z += (p4.x + p4.y) + (p4.z + p4.w);
        }
        wsZ[(long)bid * F2 + t] = z;
    }
}

// ---------------------------------------------------------------------------
// passB: in-place EXCLUSIVE prefix over n (per bh) of dS (8192 f32) and dZ (128)
// grid = BH * 8 chunks; each thread owns one float4 lane of the state.
// ---------------------------------------------------------------------------
__global__ __launch_bounds__(256) void passB(float* __restrict__ wsS,
                                             float* __restrict__ wsZ)
{
    const int t     = threadIdx.x;
    const int bh    = blockIdx.x >> 3;
    const int chunk = blockIdx.x & 7;
    const int eoff  = chunk * 1024 + t * 4;
    float4 carry = make_float4(0.f, 0.f, 0.f, 0.f);
    float zcarry = 0.f;
    const bool doZ = (chunk == 0) && (t < F2);
    for (int n = 0; n < Nc; ++n) {
        float* p = wsS + (long)(bh * Nc + n) * (F2 * Dc) + eoff;
        float4 v = *(float4*)p;
        *(float4*)p = carry;
        carry.x += v.x; carry.y += v.y; carry.z += v.z; carry.w += v.w;
        if (doZ) {
            float* pz = wsZ + (long)(bh * Nc + n) * F2 + t;
            float zv = *pz;
            *pz = zcarry;
            zcarry += zv;
        }
    }
}

// ---------------------------------------------------------------------------
// passC: per tile: phi(q), intra-block softmax branch, linear branch, combine.
// ---------------------------------------------------------------------------
__global__ __launch_bounds__(256) void passC(const float* __restrict__ Q,
                                             const float* __restrict__ K,
                                             const float* __restrict__ V,
                                             const float* __restrict__ W,
                                             const float* __restrict__ Alpha,
                                             const float* __restrict__ wsS,
                                             const float* __restrict__ wsZ,
                                             float* __restrict__ Out)
{
    // stage1: sQ [64][68] @0, sKT [64][68] @4352, sW [64][64] @8704, sZ [128] @12800
    // stage2: sV [64][68] @0, sS [128][64] @4352 (8192)
    __shared__ float lds[12928];
    float* sQ  = lds;
    float* sKT = lds + 4352;
    float* sW  = lds + 8704;
    float* sZ  = lds + 12800;
    float* sV  = lds;
    float* sS  = lds + 4352;

    const int t   = threadIdx.x;
    const int bid = blockIdx.x;
    const int bh  = bid >> 6;
    const int h   = bh & (Hc - 1);
    const long base = (long)bh * Lc * Dc + (long)(bid & 63) * Sc * Dc;

    {
        const float4* Qg = (const float4*)(Q + base);
        const float4* Wg = (const float4*)(W + (long)h * Dc * Fc);
        #pragma unroll
        for (int i = 0; i < 4; ++i) {
            int e = t + i * 256;
            float4 qv = Qg[e];
            int s = e >> 4;
            int d = (e & 15) * 4;
            *(float4*)&sQ[s * RP + d] = qv;
            *(float4*)&sW[e * 4] = Wg[e];
        }
        const float* Kg = K + base;
        #pragma unroll
        for (int i = 0; i < 16; ++i) {
            int e = t + i * 256;
            int ss = e >> 6;
            int dd = e & 63;
            sKT[dd * RP + ss] = Kg[e];   // k transposed: kT[d][s]
        }
        if (t < F2) sZ[t] = wsZ[(long)bid * F2 + t];
    }
    __syncthreads();

    const int s  = t >> 2;
    const int f0 = (t & 3) * 16;

    // u = q @ W -> phi_q (regs)
    float u[16];
    #pragma unroll
    for (int j = 0; j < 16; ++j) u[j] = 0.f;
    for (int d = 0; d < Dc; ++d) {
        float qv = sQ[s * RP + d];
        const float* wrow = &sW[d * Fc + f0];
        #pragma unroll
        for (int j4 = 0; j4 < 4; ++j4) {
            float4 w4 = *(const float4*)&wrow[j4 * 4];
            u[j4*4+0] += qv * w4.x;
            u[j4*4+1] += qv * w4.y;
            u[j4*4+2] += qv * w4.z;
            u[j4*4+3] += qv * w4.w;
        }
    }
    float mx = u[0], mn = u[0];
    #pragma unroll
    for (int j = 1; j < 16; ++j) { mx = fmaxf(mx, u[j]); mn = fminf(mn, u[j]); }
    mx = fmaxf(mx, __shfl_xor(mx, 1, 4)); mx = fmaxf(mx, __shfl_xor(mx, 2, 4));
    mn = fminf(mn, __shfl_xor(mn, 1, 4)); mn = fminf(mn, __shfl_xor(mn, 2, 4));
    float pp[16], pn[16];
    float sp = 0.f, sn = 0.f;
    #pragma unroll
    for (int j = 0; j < 16; ++j) {
        pp[j] = expf(u[j] - mx); sp += pp[j];
        pn[j] = expf(mn - u[j]); sn += pn[j];
    }
    sp += __shfl_xor(sp, 1, 4); sp += __shfl_xor(sp, 2, 4);
    sn += __shfl_xor(sn, 1, 4); sn += __shfl_xor(sn, 2, 4);
    {
        const float rpi = 1.f / sp, rni = 1.f / sn;
        #pragma unroll
        for (int j = 0; j < 16; ++j) { pp[j] *= rpi; pn[j] *= rni; }
    }

    // scores[s][tt] = (q_s . k_tt) * SCALE ; thread covers tt = f0..f0+15
    float a[16];
    #pragma unroll
    for (int j = 0; j < 16; ++j) a[j] = 0.f;
    for (int d = 0; d < Dc; ++d) {
        float qv = sQ[s * RP + d];
        const float* krow = &sKT[d * RP + f0];
        #pragma unroll
        for (int j4 = 0; j4 < 4; ++j4) {
            float4 k4 = *(const float4*)&krow[j4 * 4];
            a[j4*4+0] += qv * k4.x;
            a[j4*4+1] += qv * k4.y;
            a[j4*4+2] += qv * k4.z;
            a[j4*4+3] += qv * k4.w;
        }
    }
    float mx2;
    {
        #pragma unroll
        for (int j = 0; j < 16; ++j) a[j] *= SCALE;
        mx2 = a[0];
        #pragma unroll
        for (int j = 1; j < 16; ++j) mx2 = fmaxf(mx2, a[j]);
        mx2 = fmaxf(mx2, __shfl_xor(mx2, 1, 4));
        mx2 = fmaxf(mx2, __shfl_xor(mx2, 2, 4));
    }
    float asum = 0.f;
    #pragma unroll
    for (int j = 0; j < 16; ++j) { a[j] = expf(a[j] - mx2); asum += a[j]; }
    asum += __shfl_xor(asum, 1, 4); asum += __shfl_xor(asum, 2, 4);
    const float sden = fmaxf(asum, EPSf);

    // lin_den = max(phi_q . Z, EPS)
    float zd = 0.f;
    #pragma unroll
    for (int j = 0; j < 16; ++j)
        zd += pp[j] * sZ[f0 + j] + pn[j] * sZ[Fc + f0 + j];
    zd += __shfl_xor(zd, 1, 4); zd += __shfl_xor(zd, 2, 4);
    const float lden = fmaxf(zd, EPSf);

    __syncthreads();   // done with sQ/sKT/sW; overwrite with v and S_state
    {
        const float4* Vg = (const float4*)(V + base);
        #pragma unroll
        for (int i = 0; i < 4; ++i) {
            int e = t + i * 256;
            float4 vv = Vg[e];
            int ss = e >> 4;
            int dd = (e & 15) * 4;
            *(float4*)&sV[ss * RP + dd] = vv;
        }
        const float4* Sg = (const float4*)(wsS + (long)bid * (F2 * Dc));
        #pragma unroll
        for (int i = 0; i < 8; ++i) {
            int e = t + i * 256;
            *(float4*)&sS[e * 4] = Sg[e];
        }
    }
    __syncthreads();

    // softmax branch: acc[j] = sum_tt a_row[tt] * v[tt][f0+j]
    float acc[16];
    #pragma unroll
    for (int j = 0; j < 16; ++j) acc[j] = 0.f;
    #pragma unroll
    for (int tt = 0; tt < 64; ++tt) {
        float av = __shfl(a[tt & 15], tt >> 4, 4);
        const float* vrow = &sV[tt * RP + f0];
        #pragma unroll
        for (int j4 = 0; j4 < 4; ++j4) {
            float4 v4 = *(const float4*)&vrow[j4 * 4];
            acc[j4*4+0] += av * v4.x;
            acc[j4*4+1] += av * v4.y;
            acc[j4*4+2] += av * v4.z;
            acc[j4*4+3] += av * v4.w;
        }
    }
    const float w = 1.f / (1.f + expf(-Alpha[h]));
    #pragma unroll
    for (int j = 0; j < 16; ++j) acc[j] *= w;

    // linear branch: acc[j] += sum_fi phi_row[fi] * S[fi][f0+j]
    #pragma unroll
    for (int fi = 0; fi < 64; ++fi) {
        float pv = __shfl(pp[fi & 15], fi >> 4, 4);
        const float* srow = &sS[fi * Dc + f0];
        #pragma unroll
        for (int j4 = 0; j4 < 4; ++j4) {
            float4 s4 = *(const float4*)&srow[j4 * 4];
            acc[j4*4+0] += pv * s4.x;
            acc[j4*4+1] += pv * s4.y;
            acc[j4*4+2] += pv * s4.z;
            acc[j4*4+3] += pv * s4.w;
        }
    }
    #pragma unroll
    for (int fi = 0; fi < 64; ++fi) {
        float pv = __shfl(pn[fi & 15], fi >> 4, 4);
        const float* srow = &sS[(Fc + fi) * Dc + f0];
        #pragma unroll
        for (int j4 = 0; j4 < 4; ++j4) {
            float4 s4 = *(const float4*)&srow[j4 * 4];
            acc[j4*4+0] += pv * s4.x;
            acc[j4*4+1] += pv * s4.y;
            acc[j4*4+2] += pv * s4.z;
            acc[j4*4+3] += pv * s4.w;
        }
    }

    const float den = fmaxf(w * sden + lden, EPSf);
    const float inv = 1.f / den;
    float* outp = Out + base + (long)s * Dc + f0;
    #pragma unroll
    for (int j4 = 0; j4 < 4; ++j4) {
        float4 o;
        o.x = acc[j4*4+0] * inv;
        o.y = acc[j4*4+1] * inv;
        o.z = acc[j4*4+2] * inv;
        o.w = acc[j4*4+3] * inv;
        *(float4*)&outp[j4 * 4] = o;
    }
}

// ---------------------------------------------------------------------------
extern "C" void kernel_launch(void* const* d_in, const int* in_sizes, int n_in,
                              void* d_out, int out_size, void* d_ws, size_t ws_size,
                              hipStream_t stream)
{
    const float* q     = (const float*)d_in[0];
    const float* k     = (const float*)d_in[1];
    const float* v     = (const float*)d_in[2];
    const float* W     = (const float*)d_in[3];
    const float* alpha = (const float*)d_in[4];
    float* out = (float*)d_out;

    float* wsS = (float*)d_ws;                         // NBLK * 128*64 floats (64 MB)
    float* wsZ = wsS + (size_t)NBLK * F2 * Dc;         // NBLK * 128 floats (1 MB)

    passA<<<NBLK, 256, 0, stream>>>(k, v, W, wsS, wsZ);
    passB<<<BH * 8, 256, 0, stream>>>(wsS, wsZ);
    passC<<<NBLK, 256, 0, stream>>>(q, k, v, W, alpha, wsS, wsZ, out);
}

// Round 2
// 86.836 us; speedup vs baseline: 2.5514x; 2.5514x over previous
//
#include <hip/hip_runtime.h>
#include <hip/hip_bf16.h>
#include <math.h>

// BlockSoftmaxLinearHybrid: B=2,H=16,L=4096,D=64,F=64,S=64
constexpr int Bc = 2, Hc = 16, Lc = 4096, Dc = 64, Fc = 64;
constexpr int Sc = 64;
constexpr int Nc = Lc / Sc;      // 64
constexpr int F2 = 2 * Fc;       // 128
constexpr int BH = Bc * Hc;      // 32
constexpr int NBLK = BH * Nc;    // 2048
constexpr float EPSf = 1e-6f;
constexpr float SCALE = 0.125f;  // D^-0.5

typedef short short8 __attribute__((ext_vector_type(8)));     // 8 bf16 (4 VGPRs) MFMA A/B frag
typedef float f32x4 __attribute__((ext_vector_type(4)));      // MFMA C/D frag
typedef unsigned short ushort;
typedef ushort ushort4v __attribute__((ext_vector_type(4)));

__device__ inline ushort f2bf(float x) {            // fp32 -> bf16 RNE
    unsigned u = __builtin_bit_cast(unsigned, x);
    u = (u + 0x7fffu + ((u >> 16) & 1u)) >> 16;
    return (ushort)u;
}
__device__ inline float bf2f(ushort h) {
    return __builtin_bit_cast(float, ((unsigned)h) << 16);
}
__device__ inline f32x4 zero4() { f32x4 z = {0.f, 0.f, 0.f, 0.f}; return z; }

// MFMA 16x16x32 bf16 (m89-verified layout set):
//  A frag: lane reads A[row0 + (l&15)][k], k = chunk*8..+7 contiguous (16B)
//  B frag: from transposed store Bt[col][k]: lane reads Bt[col0+(l&15)][k]
//  D frag: lane holds D[row0 + (l>>4)*4 + r][col0 + (l&15)]
__device__ inline f32x4 mfma(short8 a, short8 b, f32x4 c) {
    return __builtin_amdgcn_mfma_f32_16x16x32_bf16(a, b, c, 0, 0, 0);
}

// LDS tiles: bf16, row-major, rowbytes = 128 ([..][64], swz mask 7) or
// 256 ([..][128], mask 15). XOR-swizzle 16B chunks: byte ^= (row&mask)<<4 (T2).
__device__ inline short8 ldfrag(const char* L, int row, int chunk, int rowbytes, int mask) {
    return *(const short8*)(L + row * rowbytes + ((chunk * 16) ^ ((row & mask) << 4)));
}

// stage row-major [64][64] fp32 global -> bf16 swizzled LDS (rowbytes 128, mask 7)
__device__ inline void stage_rm(const float* __restrict__ src, char* dst, int t) {
    #pragma unroll
    for (int i = 0; i < 4; ++i) {
        int e = t + i * 256;                 // float4 idx 0..1023
        float4 x = ((const float4*)src)[e];
        int r = e >> 4;
        int c4 = (e & 15) * 4;
        ushort4v hv;
        hv[0] = f2bf(x.x); hv[1] = f2bf(x.y); hv[2] = f2bf(x.z); hv[3] = f2bf(x.w);
        *(ushort4v*)(dst + r * 128 + ((c4 * 2) ^ ((r & 7) << 4))) = hv;
    }
}

// stage TRANSPOSED: src [64][64] fp32 row-major -> dst[j][i] = src[i][j] bf16 swz
__device__ inline void stage_tr(const float* __restrict__ src, char* dst, int t) {
    int j = t & 63, g = t >> 6;
    #pragma unroll
    for (int i = 0; i < 4; ++i) {
        int i0 = g * 4 + i * 16;
        ushort4v hv;
        #pragma unroll
        for (int jj = 0; jj < 4; ++jj) hv[jj] = f2bf(src[(i0 + jj) * 64 + j]);
        *(ushort4v*)(dst + j * 128 + ((2 * i0) ^ ((j & 7) << 4))) = hv;
    }
}

// ---------------------------------------------------------------------------
// passA: phi(k) via MFMA, dSt[d][f] = sum_s v[s][d] phi_k[s][f] (MFMA),
//        write bf16 to wsS; dZ[f] = sum_s phi_k[s][f] fp32 to wsZ.
// ---------------------------------------------------------------------------
__global__ __launch_bounds__(256) void passA(const float* __restrict__ K,
                                             const float* __restrict__ V,
                                             const float* __restrict__ W,
                                             ushort* __restrict__ wsS,
                                             float* __restrict__ wsZ)
{
    __shared__ __align__(16) char lds[40960];
    char* kR = lds;              // [64][64] k row-major (A for u)
    char* WT = lds + 8192;       // [64][64] W^T[f][d]  (B for u)
    char* vT = lds + 16384;      // [64][64] v^T[d][s]  (A for dSt)
    char* pT = lds + 24576;      // [128][64] phi_k^T[f][s] (B for dSt)

    const int t = threadIdx.x, wv = t >> 6, l = t & 63, lr = l & 15, lg = l >> 4;
    const int bid = blockIdx.x, bh = bid >> 6, h = bh & (Hc - 1);
    const long base = (long)bh * Lc * Dc + (long)(bid & 63) * Sc * Dc;

    stage_rm(K + base, kR, t);
    stage_tr(W + (long)h * Dc * Fc, WT, t);
    stage_tr(V + base, vT, t);
    __syncthreads();

    // u = k @ W  (wave wv owns rows s in [16wv, 16wv+16))
    short8 af0 = ldfrag(kR, 16 * wv + lr, lg, 128, 7);
    short8 af1 = ldfrag(kR, 16 * wv + lr, 4 + lg, 128, 7);
    f32x4 u0[4];
    #pragma unroll
    for (int tf = 0; tf < 4; ++tf) u0[tf] = zero4();
    #pragma unroll
    for (int tf = 0; tf < 4; ++tf) {
        u0[tf] = mfma(af0, ldfrag(WT, tf * 16 + lr, lg, 128, 7), u0[tf]);
        u0[tf] = mfma(af1, ldfrag(WT, tf * 16 + lr, 4 + lg, 128, 7), u0[tf]);
    }

    // row softmax(+u) / softmax(-u): lane holds rows (lg*4+r), cols tf*16+lr
    float pp[4][4], pn[4][4];
    #pragma unroll
    for (int r = 0; r < 4; ++r) {
        float mx = fmaxf(fmaxf(u0[0][r], u0[1][r]), fmaxf(u0[2][r], u0[3][r]));
        float mn = fminf(fminf(u0[0][r], u0[1][r]), fminf(u0[2][r], u0[3][r]));
        #pragma unroll
        for (int m = 1; m < 16; m <<= 1) {
            mx = fmaxf(mx, __shfl_xor(mx, m, 16));
            mn = fminf(mn, __shfl_xor(mn, m, 16));
        }
        float sp = 0.f, sn = 0.f;
        #pragma unroll
        for (int tf = 0; tf < 4; ++tf) {
            pp[tf][r] = __expf(u0[tf][r] - mx); sp += pp[tf][r];
            pn[tf][r] = __expf(mn - u0[tf][r]); sn += pn[tf][r];
        }
        #pragma unroll
        for (int m = 1; m < 16; m <<= 1) {
            sp += __shfl_xor(sp, m, 16);
            sn += __shfl_xor(sn, m, 16);
        }
        float rp = 1.f / sp, rn = 1.f / sn;
        #pragma unroll
        for (int tf = 0; tf < 4; ++tf) { pp[tf][r] *= rp; pn[tf][r] *= rn; }
    }

    // write phi_k^T[f][s]  (no region conflict; barrier orders cross-wave reads)
    #pragma unroll
    for (int tf = 0; tf < 4; ++tf)
        #pragma unroll
        for (int r = 0; r < 4; ++r) {
            int s = 16 * wv + lg * 4 + r;
            int f = tf * 16 + lr;
            *(ushort*)(pT + f * 128 + ((2 * s) ^ ((f & 7) << 4))) = f2bf(pp[tf][r]);
            int fn = 64 + f;
            *(ushort*)(pT + fn * 128 + ((2 * s) ^ ((fn & 7) << 4))) = f2bf(pn[tf][r]);
        }
    __syncthreads();

    // dSt = v^T @ phi_k : wave owns d rows [16wv, 16wv+16), 8 f-tiles, K=64
    short8 av0 = ldfrag(vT, 16 * wv + lr, lg, 128, 7);
    short8 av1 = ldfrag(vT, 16 * wv + lr, 4 + lg, 128, 7);
    f32x4 acc[8];
    #pragma unroll
    for (int tf = 0; tf < 8; ++tf) acc[tf] = zero4();
    #pragma unroll
    for (int tf = 0; tf < 8; ++tf) {
        acc[tf] = mfma(av0, ldfrag(pT, tf * 16 + lr, lg, 128, 7), acc[tf]);
        acc[tf] = mfma(av1, ldfrag(pT, tf * 16 + lr, 4 + lg, 128, 7), acc[tf]);
    }
    ushort* o = wsS + (long)bid * (F2 * Dc);
    #pragma unroll
    for (int tf = 0; tf < 8; ++tf)
        #pragma unroll
        for (int r = 0; r < 4; ++r) {
            int d = 16 * wv + lg * 4 + r;
            o[d * 128 + tf * 16 + lr] = f2bf(acc[tf][r]);
        }

    // dZ[f] = row sums of phi_k^T (fp32)
    if (t < 128) {
        float z = 0.f;
        #pragma unroll
        for (int c = 0; c < 8; ++c) {
            short8 vv = ldfrag(pT, t, c, 128, 7);
            #pragma unroll
            for (int j = 0; j < 8; ++j) z += bf2f((ushort)vv[j]);
        }
        wsZ[(long)bid * F2 + t] = z;
    }
}

// ---------------------------------------------------------------------------
// passB: exclusive prefix over n per bh. wsS bf16 (fp32 carry), wsZ fp32.
// grid = 32 bh * 8 chunks; thread owns 4 bf16 (8B).
// ---------------------------------------------------------------------------
__global__ __launch_bounds__(256) void passB(ushort* __restrict__ wsS,
                                             float* __restrict__ wsZ)
{
    const int t = threadIdx.x;
    const int bh = blockIdx.x >> 3, chunk = blockIdx.x & 7;
    const int eoff = chunk * 1024 + t * 4;
    float c0 = 0.f, c1 = 0.f, c2 = 0.f, c3 = 0.f, zc = 0.f;
    const bool doZ = (chunk == 0) && (t < F2);
    for (int n = 0; n < Nc; ++n) {
        ushort4v* p = (ushort4v*)(wsS + (long)(bh * Nc + n) * 8192 + eoff);
        ushort4v x = *p;
        ushort4v cc;
        cc[0] = f2bf(c0); cc[1] = f2bf(c1); cc[2] = f2bf(c2); cc[3] = f2bf(c3);
        *p = cc;
        c0 += bf2f(x[0]); c1 += bf2f(x[1]); c2 += bf2f(x[2]); c3 += bf2f(x[3]);
        if (doZ) {
            float* pz = wsZ + (long)(bh * Nc + n) * F2 + t;
            float zv = *pz; *pz = zc; zc += zv;
        }
    }
}

// ---------------------------------------------------------------------------
// passC: phi(q) + intra-block softmax + linear branch, all matmuls MFMA.
// ---------------------------------------------------------------------------
__global__ __launch_bounds__(256) void passC(const float* __restrict__ Q,
                                             const float* __restrict__ K,
                                             const float* __restrict__ V,
                                             const float* __restrict__ W,
                                             const float* __restrict__ Alpha,
                                             const ushort* __restrict__ wsS,
                                             const float* __restrict__ wsZ,
                                             float* __restrict__ Out)
{
    __shared__ __align__(16) char lds[49664];
    char* qR   = lds;            // [64][64] q row-major (A)
    char* WT   = lds + 8192;     // [64][64] W^T (B for u)
    char* kR   = lds + 16384;    // [64][64] k row-major (B for scores)
    char* phiB = lds;            // reuse: [64][128] phi_q row-major (A, mask 15)
    char* aB   = lds + 16384;    // reuse: [64][64] a row-major (A)
    char* vT   = lds + 24576;    // [64][64] v^T[d][t] (B for aV)
    char* St   = lds + 32768;    // [64][128] S^T[d][f] (B for lin, mask 15)
    float* sZ  = (float*)(lds + 49152);   // [128] fp32

    const int t = threadIdx.x, wv = t >> 6, l = t & 63, lr = l & 15, lg = l >> 4;
    const int bid = blockIdx.x, bh = bid >> 6, h = bh & (Hc - 1);
    const long base = (long)bh * Lc * Dc + (long)(bid & 63) * Sc * Dc;

    stage_rm(Q + base, qR, t);
    stage_tr(W + (long)h * Dc * Fc, WT, t);
    stage_rm(K + base, kR, t);
    stage_tr(V + base, vT, t);
    {   // S^T tile: bf16 global -> swizzled LDS (16B chunks)
        const ushort* g = wsS + (long)bid * (F2 * Dc);
        #pragma unroll
        for (int i = 0; i < 4; ++i) {
            int c = t + i * 256;              // 16B chunk idx 0..1023
            int d = c >> 4, fc = c & 15;
            short8 x = ((const short8*)g)[c];
            *(short8*)(St + d * 256 + ((fc * 16) ^ ((d & 15) << 4))) = x;
        }
        if (t < F2) sZ[t] = wsZ[(long)bid * F2 + t];
    }
    __syncthreads();

    // u = q@W and scores = q@k^T, wave rows [16wv,16wv+16)
    short8 aq0 = ldfrag(qR, 16 * wv + lr, lg, 128, 7);
    short8 aq1 = ldfrag(qR, 16 * wv + lr, 4 + lg, 128, 7);
    f32x4 u0[4], s0[4];
    #pragma unroll
    for (int tf = 0; tf < 4; ++tf) { u0[tf] = zero4(); s0[tf] = zero4(); }
    #pragma unroll
    for (int tf = 0; tf < 4; ++tf) {
        u0[tf] = mfma(aq0, ldfrag(WT, tf * 16 + lr, lg, 128, 7), u0[tf]);
        u0[tf] = mfma(aq1, ldfrag(WT, tf * 16 + lr, 4 + lg, 128, 7), u0[tf]);
        s0[tf] = mfma(aq0, ldfrag(kR, tf * 16 + lr, lg, 128, 7), s0[tf]);
        s0[tf] = mfma(aq1, ldfrag(kR, tf * 16 + lr, 4 + lg, 128, 7), s0[tf]);
    }

    float pp[4][4], pn[4][4], sden[4], lden[4];
    #pragma unroll
    for (int r = 0; r < 4; ++r) {
        // phi_q softmaxes
        float mx = fmaxf(fmaxf(u0[0][r], u0[1][r]), fmaxf(u0[2][r], u0[3][r]));
        float mn = fminf(fminf(u0[0][r], u0[1][r]), fminf(u0[2][r], u0[3][r]));
        #pragma unroll
        for (int m = 1; m < 16; m <<= 1) {
            mx = fmaxf(mx, __shfl_xor(mx, m, 16));
            mn = fminf(mn, __shfl_xor(mn, m, 16));
        }
        float sp = 0.f, sn = 0.f;
        #pragma unroll
        for (int tf = 0; tf < 4; ++tf) {
            pp[tf][r] = __expf(u0[tf][r] - mx); sp += pp[tf][r];
            pn[tf][r] = __expf(mn - u0[tf][r]); sn += pn[tf][r];
        }
        #pragma unroll
        for (int m = 1; m < 16; m <<= 1) {
            sp += __shfl_xor(sp, m, 16);
            sn += __shfl_xor(sn, m, 16);
        }
        float rp = 1.f / sp, rn = 1.f / sn;
        float zd = 0.f;
        #pragma unroll
        for (int tf = 0; tf < 4; ++tf) {
            pp[tf][r] *= rp; pn[tf][r] *= rn;
            zd += pp[tf][r] * sZ[tf * 16 + lr] + pn[tf][r] * sZ[64 + tf * 16 + lr];
        }
        #pragma unroll
        for (int m = 1; m < 16; m <<= 1) zd += __shfl_xor(zd, m, 16);
        lden[r] = fmaxf(zd, EPSf);

        // scores softmax (unnormalized, shared denominator)
        float sc[4];
        #pragma unroll
        for (int tf = 0; tf < 4; ++tf) sc[tf] = s0[tf][r] * SCALE;
        float m2 = fmaxf(fmaxf(sc[0], sc[1]), fmaxf(sc[2], sc[3]));
        #pragma unroll
        for (int m = 1; m < 16; m <<= 1) m2 = fmaxf(m2, __shfl_xor(m2, m, 16));
        float as = 0.f;
        #pragma unroll
        for (int tf = 0; tf < 4; ++tf) { sc[tf] = __expf(sc[tf] - m2); as += sc[tf]; }
        #pragma unroll
        for (int m = 1; m < 16; m <<= 1) as += __shfl_xor(as, m, 16);
        sden[r] = fmaxf(as, EPSf);
        #pragma unroll
        for (int tf = 0; tf < 4; ++tf) s0[tf][r] = sc[tf];   // stash exp(scores)
    }
    __syncthreads();   // all waves done reading qR/WT/kR before overwrite

    // write phi_q [64][128] and a [64][64] as bf16 A-operands
    #pragma unroll
    for (int tf = 0; tf < 4; ++tf)
        #pragma unroll
        for (int r = 0; r < 4; ++r) {
            int s = 16 * wv + lg * 4 + r;
            int f = tf * 16 + lr;
            *(ushort*)(phiB + s * 256 + ((2 * f) ^ ((s & 15) << 4))) = f2bf(pp[tf][r]);
            *(ushort*)(phiB + s * 256 + ((2 * (64 + f)) ^ ((s & 15) << 4))) = f2bf(pn[tf][r]);
            *(ushort*)(aB + s * 128 + ((2 * f) ^ ((s & 7) << 4))) = f2bf(s0[tf][r]);
        }
    __syncthreads();

    // out = w * (a @ v) + phi_q @ S
    f32x4 acc[4];
    #pragma unroll
    for (int td = 0; td < 4; ++td) acc[td] = zero4();
    short8 aa0 = ldfrag(aB, 16 * wv + lr, lg, 128, 7);
    short8 aa1 = ldfrag(aB, 16 * wv + lr, 4 + lg, 128, 7);
    #pragma unroll
    for (int td = 0; td < 4; ++td) {
        acc[td] = mfma(aa0, ldfrag(vT, td * 16 + lr, lg, 128, 7), acc[td]);
        acc[td] = mfma(aa1, ldfrag(vT, td * 16 + lr, 4 + lg, 128, 7), acc[td]);
    }
    const float w = 1.f / (1.f + __expf(-Alpha[h]));
    #pragma unroll
    for (int td = 0; td < 4; ++td)
        #pragma unroll
        for (int r = 0; r < 4; ++r) acc[td][r] *= w;

    short8 pf[4];
    #pragma unroll
    for (int kc = 0; kc < 4; ++kc) pf[kc] = ldfrag(phiB, 16 * wv + lr, kc * 4 + lg, 256, 15);
    #pragma unroll
    for (int td = 0; td < 4; ++td)
        #pragma unroll
        for (int kc = 0; kc < 4; ++kc)
            acc[td] = mfma(pf[kc], ldfrag(St, td * 16 + lr, kc * 4 + lg, 256, 15), acc[td]);

    float* op = Out + base;
    #pragma unroll
    for (int r = 0; r < 4; ++r) {
        int s = 16 * wv + lg * 4 + r;
        float den = fmaxf(w * sden[r] + lden[r], EPSf);
        float inv = 1.f / den;
        #pragma unroll
        for (int td = 0; td < 4; ++td)
            op[s * 64 + td * 16 + lr] = acc[td][r] * inv;
    }
}

// ---------------------------------------------------------------------------
extern "C" void kernel_launch(void* const* d_in, const int* in_sizes, int n_in,
                              void* d_out, int out_size, void* d_ws, size_t ws_size,
                              hipStream_t stream)
{
    const float* q     = (const float*)d_in[0];
    const float* k     = (const float*)d_in[1];
    const float* v     = (const float*)d_in[2];
    const float* W     = (const float*)d_in[3];
    const float* alpha = (const float*)d_in[4];
    float* out = (float*)d_out;

    ushort* wsSb = (ushort*)d_ws;                              // 2048*8192 bf16 = 32MB
    float*  wsZ  = (float*)((char*)d_ws + (size_t)NBLK * F2 * Dc * 2);  // 2048*128 f32 = 1MB

    passA<<<NBLK, 256, 0, stream>>>(k, v, W, wsSb, wsZ);
    passB<<<256, 256, 0, stream>>>(wsSb, wsZ);
    passC<<<NBLK, 256, 0, stream>>>(q, k, v, W, alpha, wsSb, wsZ, out);
}